// Round 2
// baseline (519.005 us; speedup 1.0000x reference)
//
#include <hip/hip_runtime.h>
#include <math.h>
#include <stdint.h>

// Problem constants
#define T_TOK 8192
#define D_DIM 7168
#define E_EXP 256
#define K_SEL 8
#define G_GRP 8
#define LG_GRP 4
#define ROUTE_SCALE 2.5f

// GEMM tiling: 128x128 block, 4 waves, wave-tile 64x64 (mi=ni=4).
// split-K=4 -> grid 512 -> 2 blocks/CU (the round-0 inter-block-overlap
// structure) with the round-1 fragment-reuse wave tile.
#define BM 128
#define BN 128
#define BK 64
#define NKT (D_DIM / BK)        // 112
#define SCALE_LO 2048.0f        // 2^11
#define INV_SCALE (1.0f / 2048.0f)

typedef _Float16 half_t;
typedef _Float16 half8 __attribute__((ext_vector_type(8)));
typedef float f32x4 __attribute__((ext_vector_type(4)));

// Wf fragment-ordered halves: [h][nb][kt][sl16][slot][8]
// offset(h,nb,kt,sl16,slot) = (((h*2+nb)*112 + kt)*16 + sl16)*512 + slot*8
#define WF_HALVES_PER_H (2 * 112 * 16 * 512)   // 1,835,008

__device__ __forceinline__ void load_lds16(const void* g, void* l) {
    __builtin_amdgcn_global_load_lds(
        (const __attribute__((address_space(1))) uint32_t*)g,
        (__attribute__((address_space(3))) uint32_t*)l, 16, 0, 0);
}

// ---------------------------------------------------------------------------
// Pre-pass: W[256][7168] fp32 -> Wf (f16 hi + scaled-lo residual), stored in
// MFMA-fragment tile order so GEMM B-staging is a pure global_load_lds copy.
// (unchanged — layout consumed identically)
// ---------------------------------------------------------------------------
__global__ __launch_bounds__(256)
void convert_W_kernel(const float* __restrict__ W, half_t* __restrict__ Wf) {
    const int u = blockIdx.x * 256 + threadIdx.x;   // 0..229375
    const int slot = u & 63;
    const int ks   = (u >> 6) & 1;
    const int p    = (u >> 7) & 7;
    const int t2   = u >> 10;          // 0..223
    const int kt   = t2 % 112;
    const int nb   = t2 / 112;
    const int e = nb * 128 + p * 16 + (slot & 15);
    const int k = kt * 64 + ks * 32 + (slot >> 4) * 8;

    const float* src = W + (size_t)e * D_DIM + k;
    float4 v0 = *(const float4*)src;
    float4 v1 = *(const float4*)(src + 4);
    float f[8] = {v0.x, v0.y, v0.z, v0.w, v1.x, v1.y, v1.z, v1.w};
    half8 hi, lo;
    #pragma unroll
    for (int j = 0; j < 8; j++) {
        const half_t h = (half_t)f[j];
        hi[j] = h;
        lo[j] = (half_t)((f[j] - (float)h) * SCALE_LO);
    }
    *(half8*)&Wf[(size_t)u * 8] = hi;
    *(half8*)&Wf[(size_t)WF_HALVES_PER_H + (size_t)u * 8] = lo;
}

// ---------------------------------------------------------------------------
// GEMM: partial logits via 3-term split-f16 MFMA, runtime split-K.
// Block: 128 tok x 128 exp x (7168/nsplit) k, 256 thr (4 waves, wave 64x64).
// Grid = 64*2*nsplit: nsplit=4 -> 512 blocks -> 2 blocks/CU; the two
// co-resident blocks have independent barriers, so one block's compute hides
// the other's barrier drain / B-load latency (m97 structure).
// LDS 64 KB: A hi+lo 32 KB + SINGLE-buffered B 32 KB (B staged between the
// two barriers via global_load_lds; the syncthreads vmcnt drain publishes it).
// XCD decode: g=bid&(2*nsplit-1) -> one (nb,split) per XCD at nsplit=4; that
// XCD's Wf slice is 917 KB -> L2-resident; co-resident CU pair shares it.
// ---------------------------------------------------------------------------
__global__ __launch_bounds__(256, 2)
void gemm_logits_f16split(const float* __restrict__ x,
                          const half_t* __restrict__ Wf,
                          float* __restrict__ planes,
                          int kt_len, int gshift) {
    __shared__ __align__(16) half_t Ah[8 * 2 * 64 * 8];   // 16 KB
    __shared__ __align__(16) half_t Al[8 * 2 * 64 * 8];   // 16 KB
    __shared__ __align__(16) half_t Bbuf[32][512];        // 32 KB (single)

    const int tid = threadIdx.x;
    const int bid = blockIdx.x;
    const int g     = bid & ((1 << gshift) - 1);
    const int j     = bid >> gshift;       // 0..63 = m_blk
    const int nb    = g & 1;
    const int split = g >> 1;              // 0..nsplit-1
    const int row0 = j * BM;
    const int ks0  = split * kt_len;

    const float* __restrict__ xA = x + (size_t)row0 * D_DIM;
    float* __restrict__ plane = planes + (size_t)split * T_TOK * E_EXP;

    const int wave = tid >> 6, lane = tid & 63;
    const int q = lane >> 4;
    const int mp0 = (wave >> 1) * 4;       // 4 mi-tiles of 16 rows
    const int np0 = (wave & 1) * 4;        // 4 ni-tiles of 16 cols

    float4 pa[4][2];
    half8 hreg[4], lreg[4];

    auto load_A = [&](int kt) {
        const int kbase = kt * BK;
        #pragma unroll
        for (int i = 0; i < 4; i++) {
            const int u = i * 256 + tid;
            const int r = u >> 3, k8 = u & 7;
            const float* p = xA + (size_t)r * D_DIM + kbase + k8 * 8;
            pa[i][0] = *(const float4*)p;
            pa[i][1] = *(const float4*)(p + 4);
        }
    };

    // fp32 -> (hi, scaled-lo) into registers; pure VALU, overlaps compute.
    auto convert_A = [&]() {
        #pragma unroll
        for (int i = 0; i < 4; i++) {
            float f[8] = {pa[i][0].x, pa[i][0].y, pa[i][0].z, pa[i][0].w,
                          pa[i][1].x, pa[i][1].y, pa[i][1].z, pa[i][1].w};
            #pragma unroll
            for (int jj = 0; jj < 8; jj++) {
                const half_t h = (half_t)f[jj];
                hreg[i][jj] = h;
                lreg[i][jj] = (half_t)((f[jj] - (float)h) * SCALE_LO);
            }
        }
    };

    // 8 ds_write_b128 between the barriers (XOR swizzle, verified layout).
    auto write_A = [&]() {
        #pragma unroll
        for (int i = 0; i < 4; i++) {
            const int u = i * 256 + tid;
            const int r = u >> 3, k8 = u & 7;
            const int m = r & 15, qq = k8 & 3, kss = k8 >> 2;
            const int slot = (m + 16 * qq) ^ k8;
            const int off = (((r >> 4) * 2 + kss) * 64 + slot) * 8;
            *(half8*)&Ah[off] = hreg[i];
            *(half8*)&Al[off] = lreg[i];
        }
    };

    auto issue_B = [&](int tt) {
        const int kt = ks0 + tt;
        half_t* bb = &Bbuf[0][0];
        #pragma unroll
        for (int i = 0; i < 8; i++) {
            const int s32 = i * 4 + wave;           // 0..31
            const int h = s32 >> 4, sl = s32 & 15;
            const half_t* src = Wf +
                ((size_t)((h * 2 + nb) * 112 + kt) * 16 + sl) * 512 + lane * 8;
            load_lds16(src, bb + s32 * 512);
        }
    };

    f32x4 ach[4][4] = {}, acc[4][4] = {};

    auto compute = [&]() {
        const half_t* bb = &Bbuf[0][0];
        #pragma unroll
        for (int ks = 0; ks < 2; ks++) {
            const int slot = lane ^ ((ks << 2) | q);
            half8 ah[4], al[4], bh[4], bl[4];
            #pragma unroll
            for (int mi = 0; mi < 4; mi++) {
                const int off = (((mp0 + mi) * 2 + ks) * 64 + slot) * 8;
                ah[mi] = *(const half8*)&Ah[off];
                al[mi] = *(const half8*)&Al[off];
            }
            #pragma unroll
            for (int ni = 0; ni < 4; ni++) {
                const int s32 = (np0 + ni) * 2 + ks;
                bh[ni] = *(const half8*)&bb[s32 * 512 + lane * 8];
                bl[ni] = *(const half8*)&bb[(16 + s32) * 512 + lane * 8];
            }
            #pragma unroll
            for (int mi = 0; mi < 4; mi++)
                #pragma unroll
                for (int ni = 0; ni < 4; ni++) {
                    ach[mi][ni] = __builtin_amdgcn_mfma_f32_16x16x32_f16(ah[mi], bh[ni], ach[mi][ni], 0, 0, 0);
                    acc[mi][ni] = __builtin_amdgcn_mfma_f32_16x16x32_f16(ah[mi], bl[ni], acc[mi][ni], 0, 0, 0);
                    acc[mi][ni] = __builtin_amdgcn_mfma_f32_16x16x32_f16(al[mi], bh[ni], acc[mi][ni], 0, 0, 0);
                }
        }
    };

    load_A(ks0);
    convert_A();

    #pragma unroll 1
    for (int tt = 0; tt < kt_len; tt++) {
        __syncthreads();                 // all waves done reading A-LDS/Bbuf(tt-1)
        write_A();                       // A(tt) regs -> LDS
        issue_B(tt);                     // B(tt) global -> LDS (latency hidden
                                         // by the co-resident block's compute)
        __syncthreads();                 // lgkm + vmcnt drained: A,B visible
        if (tt + 1 < kt_len) load_A(ks0 + tt + 1);  // issue early, lands under MFMA
        compute();
        if (tt + 1 < kt_len) convert_A();
    }

    const int col0 = nb * BN;
    #pragma unroll
    for (int mi = 0; mi < 4; mi++)
        #pragma unroll
        for (int ni = 0; ni < 4; ni++) {
            const f32x4 vh = ach[mi][ni];
            const f32x4 vc = acc[mi][ni];
            const int ex = col0 + (np0 + ni) * 16 + (lane & 15);
            #pragma unroll
            for (int r = 0; r < 4; r++) {
                const int tok = row0 + (mp0 + mi) * 16 + q * 4 + r;
                plane[(size_t)tok * E_EXP + ex] = vh[r] + vc[r] * INV_SCALE;
            }
        }
}

// ---------------------------------------------------------------------------
// Routing: one wave per token. Sums nsplit planes. No atomics.
// ---------------------------------------------------------------------------
__global__ __launch_bounds__(256)
void routing_kernel(const float* __restrict__ planes,
                    const float* __restrict__ bias,
                    float* __restrict__ out_w,
                    float* __restrict__ out_i,
                    int nsplit) {
    const int wave = threadIdx.x >> 6;
    const int lane = threadIdx.x & 63;
    const int t    = blockIdx.x * 4 + wave;

    float lg[4] = {0.f, 0.f, 0.f, 0.f};
    for (int s = 0; s < nsplit; s++) {
        const float4 l = *(const float4*)(planes + (size_t)s * T_TOK * E_EXP +
                                          (size_t)t * E_EXP + lane * 4);
        lg[0] += l.x; lg[1] += l.y; lg[2] += l.z; lg[3] += l.w;
    }
    const float4 bi = *(const float4*)(bias + lane * 4);

    float orig[4], s[4];
    #pragma unroll
    for (int j = 0; j < 4; j++)
        orig[j] = 1.0f / (1.0f + expf(-lg[j]));
    s[0] = orig[0] + bi.x; s[1] = orig[1] + bi.y;
    s[2] = orig[2] + bi.z; s[3] = orig[3] + bi.w;

    float p1 = fmaxf(s[0], s[1]), p2 = fminf(s[0], s[1]);
    float q1 = fmaxf(s[2], s[3]), q2 = fminf(s[2], s[3]);
    float m1 = fmaxf(p1, q1);
    float m2 = fmaxf(fminf(p1, q1), (p1 >= q1) ? p2 : q2);

    #pragma unroll
    for (int off = 1; off <= 4; off <<= 1) {
        float o1 = __shfl_xor(m1, off);
        float o2 = __shfl_xor(m2, off);
        float M1 = fmaxf(m1, o1);
        float M2 = fmaxf(fminf(m1, o1), (m1 >= o1) ? m2 : o2);
        m1 = M1; m2 = M2;
    }
    const float gscore = m1 + m2;

    const int g = lane >> 3;
    int cnt = 0;
    #pragma unroll
    for (int j = 0; j < G_GRP; j++) {
        float gj = __shfl(gscore, j * 8);
        cnt += (gj > gscore || (gj == gscore && j < g)) ? 1 : 0;
    }
    const bool keep = (cnt < LG_GRP);

    float smask[4];
    #pragma unroll
    for (int j = 0; j < 4; j++) smask[j] = keep ? s[j] : -INFINITY;

    float wsum = 0.0f, my_o = 0.0f;
    int my_i = 0;

    #pragma unroll
    for (int k = 0; k < K_SEL; k++) {
        float bv = smask[0]; float bo = orig[0]; int bs = 0;
        if (smask[1] > bv) { bv = smask[1]; bo = orig[1]; bs = 1; }
        if (smask[2] > bv) { bv = smask[2]; bo = orig[2]; bs = 2; }
        if (smask[3] > bv) { bv = smask[3]; bo = orig[3]; bs = 3; }
        int bidx = lane * 4 + bs;

        #pragma unroll
        for (int off = 32; off >= 1; off >>= 1) {
            float ov = __shfl_xor(bv, off);
            float oo = __shfl_xor(bo, off);
            int   oi = __shfl_xor(bidx, off);
            if (ov > bv || (ov == bv && oi < bidx)) { bv = ov; bo = oo; bidx = oi; }
        }
        wsum += bo;
        if (lane == k) { my_o = bo; my_i = bidx; }
        if ((bidx >> 2) == lane) {
            const int sl = bidx & 3;
            smask[0] = (sl == 0) ? -INFINITY : smask[0];
            smask[1] = (sl == 1) ? -INFINITY : smask[1];
            smask[2] = (sl == 2) ? -INFINITY : smask[2];
            smask[3] = (sl == 3) ? -INFINITY : smask[3];
        }
    }

    if (lane < K_SEL) {
        out_w[(size_t)t * K_SEL + lane] = my_o * ROUTE_SCALE / wsum;
        out_i[(size_t)t * K_SEL + lane] = (float)my_i;
    }
}

// ---------------------------------------------------------------------------
// Counts: block e scans all T*K indices for expert e. L2-hot, zero atomics.
// ---------------------------------------------------------------------------
__global__ __launch_bounds__(256)
void count_kernel(const float* __restrict__ idxf, float* __restrict__ out_c) {
    const float fe = (float)blockIdx.x;
    int c = 0;
    const float4* p = (const float4*)idxf;          // T*K/4 = 16384
    for (int i = threadIdx.x; i < (T_TOK * K_SEL / 4); i += 256) {
        float4 v = p[i];
        c += (v.x == fe) + (v.y == fe) + (v.z == fe) + (v.w == fe);
    }
    __shared__ int red[4];
    #pragma unroll
    for (int off = 32; off >= 1; off >>= 1) c += __shfl_down(c, off);
    if ((threadIdx.x & 63) == 0) red[threadIdx.x >> 6] = c;
    __syncthreads();
    if (threadIdx.x == 0)
        out_c[blockIdx.x] = (float)(red[0] + red[1] + red[2] + red[3]);
}

// ---------------- launch ----------------
extern "C" void kernel_launch(void* const* d_in, const int* in_sizes, int n_in,
                              void* d_out, int out_size, void* d_ws, size_t ws_size,
                              hipStream_t stream) {
    const float* x    = (const float*)d_in[0];
    const float* W    = (const float*)d_in[1];
    const float* bias = (const float*)d_in[2];

    float* out   = (float*)d_out;
    float* out_w = out;
    float* out_i = out + (size_t)T_TOK * K_SEL;
    float* out_c = out + (size_t)2 * T_TOK * K_SEL;

    const size_t planeN  = (size_t)T_TOK * E_EXP;              // floats per plane
    const size_t wfBytes = (size_t)2 * WF_HALVES_PER_H * sizeof(half_t);

    // split-K=4 (grid 512, 2 blocks/CU) if workspace fits; else split-K=2.
    int nsplit = 4;
    if (ws_size != 0 && ws_size < 4 * planeN * sizeof(float) + wfBytes)
        nsplit = 2;
    const int gshift = (nsplit == 4) ? 3 : 2;
    const int kt_len = NKT / nsplit;
    const int grid   = 64 * 2 * nsplit;

    float* planes = (float*)d_ws;
    half_t* Wf    = (half_t*)(planes + (size_t)nsplit * planeN);

    hipLaunchKernelGGL(convert_W_kernel, dim3(896), dim3(256), 0, stream, W, Wf);
    hipLaunchKernelGGL(gemm_logits_f16split, dim3(grid), dim3(256), 0, stream,
                       x, Wf, planes, kt_len, gshift);
    hipLaunchKernelGGL(routing_kernel, dim3(T_TOK / 4), dim3(256), 0, stream,
                       planes, bias, out_w, out_i, nsplit);
    hipLaunchKernelGGL(count_kernel, dim3(E_EXP), dim3(256), 0, stream,
                       out_i, out_c);
}

// Round 3
// 415.028 us; speedup vs baseline: 1.2505x; 1.2505x over previous
//
#include <hip/hip_runtime.h>
#include <math.h>
#include <stdint.h>

// Problem constants
#define T_TOK 8192
#define D_DIM 7168
#define E_EXP 256
#define K_SEL 8
#define G_GRP 8
#define LG_GRP 4
#define ROUTE_SCALE 2.5f

// GEMM tiling: 128x128 block, 4 waves (2x2), wave-tile 64x64.
// A: global->regs->cvt->LDS (R0/R1-verified swizzle). B: direct L2->regs per
// wave (no LDS round trip) — per-XCD Wf slice is 917 KB, L2-resident.
// split-K=4 -> grid 512 -> 2 blocks/CU (inter-block overlap hides barriers).
#define BM 128
#define BN 128
#define BK 64
#define NKT (D_DIM / BK)        // 112
#define SCALE_LO 2048.0f        // 2^11
#define INV_SCALE (1.0f / 2048.0f)

typedef _Float16 half_t;
typedef _Float16 half8 __attribute__((ext_vector_type(8)));
typedef float f32x4 __attribute__((ext_vector_type(4)));

// Wf fragment-ordered halves: [h][nb][kt][sl16][slot][8]
// offset(h,nb,kt,sl16,slot) = (((h*2+nb)*112 + kt)*16 + sl16)*512 + slot*8
#define WF_HALVES_PER_H (2 * 112 * 16 * 512)   // 1,835,008

// ---------------------------------------------------------------------------
// Pre-pass: W[256][7168] fp32 -> Wf (f16 hi + scaled-lo residual), stored in
// MFMA-fragment tile order. (unchanged — layout consumed identically)
// ---------------------------------------------------------------------------
__global__ __launch_bounds__(256)
void convert_W_kernel(const float* __restrict__ W, half_t* __restrict__ Wf) {
    const int u = blockIdx.x * 256 + threadIdx.x;   // 0..229375
    const int slot = u & 63;
    const int ks   = (u >> 6) & 1;
    const int p    = (u >> 7) & 7;
    const int t2   = u >> 10;          // 0..223
    const int kt   = t2 % 112;
    const int nb   = t2 / 112;
    const int e = nb * 128 + p * 16 + (slot & 15);
    const int k = kt * 64 + ks * 32 + (slot >> 4) * 8;

    const float* src = W + (size_t)e * D_DIM + k;
    float4 v0 = *(const float4*)src;
    float4 v1 = *(const float4*)(src + 4);
    float f[8] = {v0.x, v0.y, v0.z, v0.w, v1.x, v1.y, v1.z, v1.w};
    half8 hi, lo;
    #pragma unroll
    for (int j = 0; j < 8; j++) {
        const half_t h = (half_t)f[j];
        hi[j] = h;
        lo[j] = (half_t)((f[j] - (float)h) * SCALE_LO);
    }
    *(half8*)&Wf[(size_t)u * 8] = hi;
    *(half8*)&Wf[(size_t)WF_HALVES_PER_H + (size_t)u * 8] = lo;
}

// ---------------------------------------------------------------------------
// GEMM: partial logits via 3-term split-f16 MFMA, runtime split-K.
// LDS = A hi+lo only (32 KB). Barrier window = A convert + 8 ds_write_b128,
// no global op ever drains inside the window (R2's failure mode removed).
// B fragments load straight from Wf (L2) into regs inside compute; the
// vmcnt waits sit in front of the MFMAs and are covered by the co-resident
// block's compute. A(tt+1) global loads issue between the two ks-phases.
// XCD decode: g=bid&7 at nsplit=4 -> one (nb,split) per XCD; Wf slice 917 KB.
// ---------------------------------------------------------------------------
__global__ __launch_bounds__(256, 2)
void gemm_logits_f16split(const float* __restrict__ x,
                          const half_t* __restrict__ Wf,
                          float* __restrict__ planes,
                          int kt_len, int gshift) {
    __shared__ __align__(16) half_t Ah[8 * 2 * 64 * 8];   // 16 KB
    __shared__ __align__(16) half_t Al[8 * 2 * 64 * 8];   // 16 KB

    const int tid = threadIdx.x;
    const int bid = blockIdx.x;
    const int g     = bid & ((1 << gshift) - 1);
    const int j     = bid >> gshift;       // 0..63 = m_blk
    const int nb    = g & 1;
    const int split = g >> 1;              // 0..nsplit-1
    const int row0 = j * BM;
    const int ks0  = split * kt_len;

    const float* __restrict__ xA = x + (size_t)row0 * D_DIM;
    float* __restrict__ plane = planes + (size_t)split * T_TOK * E_EXP;

    const int wave = tid >> 6, lane = tid & 63;
    const int q = lane >> 4;
    const int mp0 = (wave >> 1) * 4;       // 4 mi-tiles of 16 rows
    const int np0 = (wave & 1) * 4;        // 4 ni-tiles of 16 cols

    // Per-wave B base pointers (kt-invariant parts). s32 = (np0+ni)*2+ks in
    // 0..15, so sl == s32; hi plane h=0 -> (nb*112+kt), lo h=1 -> ((2+nb)*112+kt).
    const half_t* __restrict__ wfh = Wf + ((size_t)nb * 112) * 16 * 512 + (size_t)lane * 8;
    const half_t* __restrict__ wfl = Wf + ((size_t)(2 + nb) * 112) * 16 * 512 + (size_t)lane * 8;

    float4 pa[4][2];

    auto load_A = [&](int kt) {
        const int kbase = kt * BK;
        #pragma unroll
        for (int i = 0; i < 4; i++) {
            const int u = i * 256 + tid;
            const int r = u >> 3, k8 = u & 7;
            const float* p = xA + (size_t)r * D_DIM + kbase + k8 * 8;
            pa[i][0] = *(const float4*)p;
            pa[i][1] = *(const float4*)(p + 4);
        }
    };

    // Convert fp32 -> (hi, scaled-lo) and ds_write (XOR swizzle, verified).
    auto stage_A = [&]() {
        #pragma unroll
        for (int i = 0; i < 4; i++) {
            const int u = i * 256 + tid;
            const int r = u >> 3, k8 = u & 7;
            float f[8] = {pa[i][0].x, pa[i][0].y, pa[i][0].z, pa[i][0].w,
                          pa[i][1].x, pa[i][1].y, pa[i][1].z, pa[i][1].w};
            half8 hi, lo;
            #pragma unroll
            for (int jj = 0; jj < 8; jj++) {
                const half_t h = (half_t)f[jj];
                hi[jj] = h;
                lo[jj] = (half_t)((f[jj] - (float)h) * SCALE_LO);
            }
            const int m = r & 15, qq = k8 & 3, kss = k8 >> 2;
            const int slot = (m + 16 * qq) ^ k8;
            const int off = (((r >> 4) * 2 + kss) * 64 + slot) * 8;
            *(half8*)&Ah[off] = hi;
            *(half8*)&Al[off] = lo;
        }
    };

    f32x4 ach[4][4] = {}, acc[4][4] = {};

    auto compute = [&](int kt, bool pref, int ktn) {
        // B fragments: direct global loads (L2-hot). Issue all 16 up front so
        // the first-MFMA vmcnt wait covers as many as possible.
        half8 bh[4][2], bl[4][2];
        const size_t ktoff = (size_t)kt * (16 * 512);
        #pragma unroll
        for (int ni = 0; ni < 4; ni++)
            #pragma unroll
            for (int ks = 0; ks < 2; ks++) {
                const int s32 = (np0 + ni) * 2 + ks;   // 0..15 == sl
                bh[ni][ks] = *(const half8*)(wfh + ktoff + (size_t)s32 * 512);
                bl[ni][ks] = *(const half8*)(wfl + ktoff + (size_t)s32 * 512);
            }
        #pragma unroll
        for (int ks = 0; ks < 2; ks++) {
            const int slot = lane ^ ((ks << 2) | q);
            half8 ah[4], al[4];
            #pragma unroll
            for (int mi = 0; mi < 4; mi++) {
                const int off = (((mp0 + mi) * 2 + ks) * 64 + slot) * 8;
                ah[mi] = *(const half8*)&Ah[off];
                al[mi] = *(const half8*)&Al[off];
            }
            #pragma unroll
            for (int mi = 0; mi < 4; mi++)
                #pragma unroll
                for (int ni = 0; ni < 4; ni++) {
                    ach[mi][ni] = __builtin_amdgcn_mfma_f32_16x16x32_f16(ah[mi], bh[ni][ks], ach[mi][ni], 0, 0, 0);
                    acc[mi][ni] = __builtin_amdgcn_mfma_f32_16x16x32_f16(ah[mi], bl[ni][ks], acc[mi][ni], 0, 0, 0);
                    acc[mi][ni] = __builtin_amdgcn_mfma_f32_16x16x32_f16(al[mi], bh[ni][ks], acc[mi][ni], 0, 0, 0);
                }
            // A(tt+1) prefetch between the two ks-phases: ks=0 B-regs are
            // dead by the time these land; latency drains at next stage_A.
            if (ks == 0 && pref) load_A(ktn);
        }
    };

    load_A(ks0);

    #pragma unroll 1
    for (int tt = 0; tt < kt_len; tt++) {
        __syncthreads();                 // waves done reading A-LDS (tt-1)
        stage_A();                       // cvt + 8 ds_write_b128 only
        __syncthreads();                 // lgkm drain only — no vmcnt here
        compute(ks0 + tt, tt + 1 < kt_len, ks0 + tt + 1);
    }

    const int col0 = nb * BN;
    #pragma unroll
    for (int mi = 0; mi < 4; mi++)
        #pragma unroll
        for (int ni = 0; ni < 4; ni++) {
            const f32x4 vh = ach[mi][ni];
            const f32x4 vc = acc[mi][ni];
            const int ex = col0 + (np0 + ni) * 16 + (lane & 15);
            #pragma unroll
            for (int r = 0; r < 4; r++) {
                const int tok = row0 + (mp0 + mi) * 16 + q * 4 + r;
                plane[(size_t)tok * E_EXP + ex] = vh[r] + vc[r] * INV_SCALE;
            }
        }
}

// ---------------------------------------------------------------------------
// Routing: one wave per token. Sums nsplit planes. No atomics.
// ---------------------------------------------------------------------------
__global__ __launch_bounds__(256)
void routing_kernel(const float* __restrict__ planes,
                    const float* __restrict__ bias,
                    float* __restrict__ out_w,
                    float* __restrict__ out_i,
                    int nsplit) {
    const int wave = threadIdx.x >> 6;
    const int lane = threadIdx.x & 63;
    const int t    = blockIdx.x * 4 + wave;

    float lg[4] = {0.f, 0.f, 0.f, 0.f};
    for (int s = 0; s < nsplit; s++) {
        const float4 l = *(const float4*)(planes + (size_t)s * T_TOK * E_EXP +
                                          (size_t)t * E_EXP + lane * 4);
        lg[0] += l.x; lg[1] += l.y; lg[2] += l.z; lg[3] += l.w;
    }
    const float4 bi = *(const float4*)(bias + lane * 4);

    float orig[4], s[4];
    #pragma unroll
    for (int j = 0; j < 4; j++)
        orig[j] = 1.0f / (1.0f + expf(-lg[j]));
    s[0] = orig[0] + bi.x; s[1] = orig[1] + bi.y;
    s[2] = orig[2] + bi.z; s[3] = orig[3] + bi.w;

    float p1 = fmaxf(s[0], s[1]), p2 = fminf(s[0], s[1]);
    float q1 = fmaxf(s[2], s[3]), q2 = fminf(s[2], s[3]);
    float m1 = fmaxf(p1, q1);
    float m2 = fmaxf(fminf(p1, q1), (p1 >= q1) ? p2 : q2);

    #pragma unroll
    for (int off = 1; off <= 4; off <<= 1) {
        float o1 = __shfl_xor(m1, off);
        float o2 = __shfl_xor(m2, off);
        float M1 = fmaxf(m1, o1);
        float M2 = fmaxf(fminf(m1, o1), (m1 >= o1) ? m2 : o2);
        m1 = M1; m2 = M2;
    }
    const float gscore = m1 + m2;

    const int g = lane >> 3;
    int cnt = 0;
    #pragma unroll
    for (int j = 0; j < G_GRP; j++) {
        float gj = __shfl(gscore, j * 8);
        cnt += (gj > gscore || (gj == gscore && j < g)) ? 1 : 0;
    }
    const bool keep = (cnt < LG_GRP);

    float smask[4];
    #pragma unroll
    for (int j = 0; j < 4; j++) smask[j] = keep ? s[j] : -INFINITY;

    float wsum = 0.0f, my_o = 0.0f;
    int my_i = 0;

    #pragma unroll
    for (int k = 0; k < K_SEL; k++) {
        float bv = smask[0]; float bo = orig[0]; int bs = 0;
        if (smask[1] > bv) { bv = smask[1]; bo = orig[1]; bs = 1; }
        if (smask[2] > bv) { bv = smask[2]; bo = orig[2]; bs = 2; }
        if (smask[3] > bv) { bv = smask[3]; bo = orig[3]; bs = 3; }
        int bidx = lane * 4 + bs;

        #pragma unroll
        for (int off = 32; off >= 1; off >>= 1) {
            float ov = __shfl_xor(bv, off);
            float oo = __shfl_xor(bo, off);
            int   oi = __shfl_xor(bidx, off);
            if (ov > bv || (ov == bv && oi < bidx)) { bv = ov; bo = oo; bidx = oi; }
        }
        wsum += bo;
        if (lane == k) { my_o = bo; my_i = bidx; }
        if ((bidx >> 2) == lane) {
            const int sl = bidx & 3;
            smask[0] = (sl == 0) ? -INFINITY : smask[0];
            smask[1] = (sl == 1) ? -INFINITY : smask[1];
            smask[2] = (sl == 2) ? -INFINITY : smask[2];
            smask[3] = (sl == 3) ? -INFINITY : smask[3];
        }
    }

    if (lane < K_SEL) {
        out_w[(size_t)t * K_SEL + lane] = my_o * ROUTE_SCALE / wsum;
        out_i[(size_t)t * K_SEL + lane] = (float)my_i;
    }
}

// ---------------------------------------------------------------------------
// Counts: block e scans all T*K indices for expert e. L2-hot, zero atomics.
// ---------------------------------------------------------------------------
__global__ __launch_bounds__(256)
void count_kernel(const float* __restrict__ idxf, float* __restrict__ out_c) {
    const float fe = (float)blockIdx.x;
    int c = 0;
    const float4* p = (const float4*)idxf;          // T*K/4 = 16384
    for (int i = threadIdx.x; i < (T_TOK * K_SEL / 4); i += 256) {
        float4 v = p[i];
        c += (v.x == fe) + (v.y == fe) + (v.z == fe) + (v.w == fe);
    }
    __shared__ int red[4];
    #pragma unroll
    for (int off = 32; off >= 1; off >>= 1) c += __shfl_down(c, off);
    if ((threadIdx.x & 63) == 0) red[threadIdx.x >> 6] = c;
    __syncthreads();
    if (threadIdx.x == 0)
        out_c[blockIdx.x] = (float)(red[0] + red[1] + red[2] + red[3]);
}

// ---------------- launch ----------------
extern "C" void kernel_launch(void* const* d_in, const int* in_sizes, int n_in,
                              void* d_out, int out_size, void* d_ws, size_t ws_size,
                              hipStream_t stream) {
    const float* x    = (const float*)d_in[0];
    const float* W    = (const float*)d_in[1];
    const float* bias = (const float*)d_in[2];

    float* out   = (float*)d_out;
    float* out_w = out;
    float* out_i = out + (size_t)T_TOK * K_SEL;
    float* out_c = out + (size_t)2 * T_TOK * K_SEL;

    const size_t planeN  = (size_t)T_TOK * E_EXP;              // floats per plane
    const size_t wfBytes = (size_t)2 * WF_HALVES_PER_H * sizeof(half_t);

    // split-K=4 (grid 512, 2 blocks/CU) if workspace fits; else split-K=2.
    int nsplit = 4;
    if (ws_size != 0 && ws_size < 4 * planeN * sizeof(float) + wfBytes)
        nsplit = 2;
    const int gshift = (nsplit == 4) ? 3 : 2;
    const int kt_len = NKT / nsplit;
    const int grid   = 64 * 2 * nsplit;

    float* planes = (float*)d_ws;
    half_t* Wf    = (half_t*)(planes + (size_t)nsplit * planeN);

    hipLaunchKernelGGL(convert_W_kernel, dim3(896), dim3(256), 0, stream, W, Wf);
    hipLaunchKernelGGL(gemm_logits_f16split, dim3(grid), dim3(256), 0, stream,
                       x, Wf, planes, kt_len, gshift);
    hipLaunchKernelGGL(routing_kernel, dim3(T_TOK / 4), dim3(256), 0, stream,
                       planes, bias, out_w, out_i, nsplit);
    hipLaunchKernelGGL(count_kernel, dim3(E_EXP), dim3(256), 0, stream,
                       out_i, out_c);
}

// Round 4
// 413.491 us; speedup vs baseline: 1.2552x; 1.0037x over previous
//
#include <hip/hip_runtime.h>
#include <math.h>
#include <stdint.h>

// Problem constants
#define T_TOK 8192
#define D_DIM 7168
#define E_EXP 256
#define K_SEL 8
#define G_GRP 8
#define LG_GRP 4
#define ROUTE_SCALE 2.5f

// GEMM tiling: R0's proven shape — BM=64, BN=128, 4 waves, wave-tile 32x64 —
// with LDS cut to 48 KB (B-lo direct from L2) so 3 blocks/CU are resident
// (12 waves/CU vs R0's 8: occupancy was the binding resource, not any pipe).
#define BM 64
#define BN 128
#define BK 64
#define NKT (D_DIM / BK)        // 112
#define SCALE_LO 2048.0f        // 2^11
#define INV_SCALE (1.0f / 2048.0f)

typedef _Float16 half_t;
typedef _Float16 half8 __attribute__((ext_vector_type(8)));
typedef float f32x4 __attribute__((ext_vector_type(4)));

// Wf fragment-ordered halves: [h][nb][kt][sl16][slot][8]
// offset(h,nb,kt,sl16,slot) = (((h*2+nb)*112 + kt)*16 + sl16)*512 + slot*8
#define WF_HALVES_PER_H (2 * 112 * 16 * 512)   // 1,835,008

__device__ __forceinline__ void load_lds16(const void* g, void* l) {
    __builtin_amdgcn_global_load_lds(
        (const __attribute__((address_space(1))) uint32_t*)g,
        (__attribute__((address_space(3))) uint32_t*)l, 16, 0, 0);
}

// ---------------------------------------------------------------------------
// Pre-pass: W[256][7168] fp32 -> Wf (f16 hi + scaled-lo residual), stored in
// MFMA-fragment tile order. (unchanged — layout consumed identically)
// ---------------------------------------------------------------------------
__global__ __launch_bounds__(256)
void convert_W_kernel(const float* __restrict__ W, half_t* __restrict__ Wf) {
    const int u = blockIdx.x * 256 + threadIdx.x;   // 0..229375
    const int slot = u & 63;
    const int ks   = (u >> 6) & 1;
    const int p    = (u >> 7) & 7;
    const int t2   = u >> 10;          // 0..223
    const int kt   = t2 % 112;
    const int nb   = t2 / 112;
    const int e = nb * 128 + p * 16 + (slot & 15);
    const int k = kt * 64 + ks * 32 + (slot >> 4) * 8;

    const float* src = W + (size_t)e * D_DIM + k;
    float4 v0 = *(const float4*)src;
    float4 v1 = *(const float4*)(src + 4);
    float f[8] = {v0.x, v0.y, v0.z, v0.w, v1.x, v1.y, v1.z, v1.w};
    half8 hi, lo;
    #pragma unroll
    for (int j = 0; j < 8; j++) {
        const half_t h = (half_t)f[j];
        hi[j] = h;
        lo[j] = (half_t)((f[j] - (float)h) * SCALE_LO);
    }
    *(half8*)&Wf[(size_t)u * 8] = hi;
    *(half8*)&Wf[(size_t)WF_HALVES_PER_H + (size_t)u * 8] = lo;
}

// ---------------------------------------------------------------------------
// GEMM: partial logits via 3-term split-f16 MFMA, runtime split-K (3 uneven).
// Structure = R0's verified 2-barrier loop verbatim, except:
//   * Bbuf holds HI plane only, double-buffered (32 KB); LO plane (bl) loads
//     direct L2->regs (R3-verified addressing) — LDS 80->48 KB -> 3 blocks/CU.
//   * Issue order in compute: bl x8 FIRST, then B-hi(t+1)/A(t+1) prefetch,
//     then MFMAs — so bl is consumable at a counted vmcnt (never drains the
//     prefetch), and the prefetch stays in flight until next-iter's barrier.
// ---------------------------------------------------------------------------
__global__ __launch_bounds__(256, 3)
void gemm_logits_f16split(const float* __restrict__ x,
                          const half_t* __restrict__ Wf,
                          float* __restrict__ planes,
                          int nsplit) {
    __shared__ __align__(16) half_t Ah[4 * 2 * 64 * 8];   // 8 KB
    __shared__ __align__(16) half_t Al[4 * 2 * 64 * 8];   // 8 KB
    __shared__ __align__(16) half_t Bbuf[2][16][512];     // 32 KB (hi only)

    const int tid = threadIdx.x;
    const int bid = blockIdx.x;
    const int nmod  = 2 * nsplit;
    const int g     = bid % nmod;
    const int j     = bid / nmod;          // 0..127 = m_blk
    const int nb    = g & 1;
    const int split = g >> 1;              // 0..nsplit-1
    const int row0 = j * BM;

    int ks0, kt_len;
    if (nsplit == 3) { ks0 = split * 38 - (split == 2 ? 1 : 0);
                       kt_len = split ? 37 : 38; }        // 38+37+37 = 112
    else             { ks0 = split * (NKT / nsplit);
                       kt_len = NKT / nsplit; }

    const float* __restrict__ xA = x + (size_t)row0 * D_DIM;
    float* __restrict__ plane = planes + (size_t)split * T_TOK * E_EXP;

    const int wave = tid >> 6, lane = tid & 63;
    const int q = lane >> 4;
    const int mp0 = (wave >> 1) * 2;       // 2 mi-tiles of 16 rows
    const int np0 = (wave & 1) * 4;        // 4 ni-tiles of 16 cols

    // lo-plane direct-load base (R3-verified): h=1 -> (2+nb)*112 block.
    const half_t* __restrict__ wfl = Wf + ((size_t)(2 + nb) * 112) * 16 * 512
                                        + (size_t)lane * 8;

    float4 pa[2][2];

    auto load_A = [&](int kt) {
        const int kbase = kt * BK;
        #pragma unroll
        for (int i = 0; i < 2; i++) {
            const int u = i * 256 + tid;
            const int r = u >> 3, k8 = u & 7;
            const float* p = xA + (size_t)r * D_DIM + kbase + k8 * 8;
            pa[i][0] = *(const float4*)p;
            pa[i][1] = *(const float4*)(p + 4);
        }
    };

    auto stage_A = [&]() {
        #pragma unroll
        for (int i = 0; i < 2; i++) {
            const int u = i * 256 + tid;
            const int r = u >> 3, k8 = u & 7;
            float f[8] = {pa[i][0].x, pa[i][0].y, pa[i][0].z, pa[i][0].w,
                          pa[i][1].x, pa[i][1].y, pa[i][1].z, pa[i][1].w};
            half8 hi, lo;
            #pragma unroll
            for (int jj = 0; jj < 8; jj++) {
                const half_t h = (half_t)f[jj];
                hi[jj] = h;
                lo[jj] = (half_t)((f[jj] - (float)h) * SCALE_LO);
            }
            const int m = r & 15, qq = k8 & 3, kss = k8 >> 2;
            const int slot = (m + 16 * qq) ^ k8;
            const int off = (((r >> 4) * 2 + kss) * 64 + slot) * 8;
            *(half8*)&Ah[off] = hi;
            *(half8*)&Al[off] = lo;
        }
    };

    // B-hi global->LDS (double-buffered): 16 slices, 4 iters x 4 waves.
    auto issue_B = [&](int tt) {
        const int kt = ks0 + tt;
        half_t* bb = &Bbuf[tt & 1][0][0];
        #pragma unroll
        for (int i = 0; i < 4; i++) {
            const int sl = i * 4 + wave;            // 0..15 (hi slices only)
            const half_t* src = Wf +
                ((size_t)(nb * 112 + kt) * 16 + sl) * 512 + lane * 8;
            load_lds16(src, bb + sl * 512);
        }
    };

    f32x4 ach[2][4] = {}, acc[2][4] = {};

    auto compute = [&](int tt, bool pref) {
        const int kt = ks0 + tt;
        const half_t* bb = &Bbuf[tt & 1][0][0];

        // 1) bl direct loads first (oldest in vm queue -> counted consumption)
        half8 bl[4][2];
        const size_t ktoff = (size_t)kt * (16 * 512);
        #pragma unroll
        for (int ni = 0; ni < 4; ni++)
            #pragma unroll
            for (int ks = 0; ks < 2; ks++) {
                const int s32 = (np0 + ni) * 2 + ks;   // 0..15
                bl[ni][ks] = *(const half8*)(wfl + ktoff + (size_t)s32 * 512);
            }
        // 2) prefetch next tile (in flight across next barrier, R0 discipline)
        if (pref) {
            issue_B(tt + 1);
            load_A(ks0 + tt + 1);
        }
        // 3) MFMAs
        #pragma unroll
        for (int ks = 0; ks < 2; ks++) {
            const int slot = lane ^ ((ks << 2) | q);
            half8 ah[2], al[2], bh[4];
            #pragma unroll
            for (int mi = 0; mi < 2; mi++) {
                const int off = (((mp0 + mi) * 2 + ks) * 64 + slot) * 8;
                ah[mi] = *(const half8*)&Ah[off];
                al[mi] = *(const half8*)&Al[off];
            }
            #pragma unroll
            for (int ni = 0; ni < 4; ni++) {
                const int s32 = (np0 + ni) * 2 + ks;
                bh[ni] = *(const half8*)&bb[s32 * 512 + lane * 8];
            }
            #pragma unroll
            for (int mi = 0; mi < 2; mi++)
                #pragma unroll
                for (int ni = 0; ni < 4; ni++) {
                    ach[mi][ni] = __builtin_amdgcn_mfma_f32_16x16x32_f16(ah[mi], bh[ni], ach[mi][ni], 0, 0, 0);
                    acc[mi][ni] = __builtin_amdgcn_mfma_f32_16x16x32_f16(ah[mi], bl[ni][ks], acc[mi][ni], 0, 0, 0);
                    acc[mi][ni] = __builtin_amdgcn_mfma_f32_16x16x32_f16(al[mi], bh[ni], acc[mi][ni], 0, 0, 0);
                }
        }
    };

    issue_B(0);
    load_A(ks0);

    #pragma unroll 1
    for (int tt = 0; tt < kt_len; tt++) {
        __syncthreads();                 // drains B-hi(tt)+A(tt) prefetch
        stage_A();
        __syncthreads();                 // A ds_writes visible; vm queue empty
        compute(tt, tt + 1 < kt_len);
    }

    const int col0 = nb * BN;
    #pragma unroll
    for (int mi = 0; mi < 2; mi++)
        #pragma unroll
        for (int ni = 0; ni < 4; ni++) {
            const f32x4 vh = ach[mi][ni];
            const f32x4 vc = acc[mi][ni];
            const int ex = col0 + (np0 + ni) * 16 + (lane & 15);
            #pragma unroll
            for (int r = 0; r < 4; r++) {
                const int tok = row0 + (mp0 + mi) * 16 + q * 4 + r;
                plane[(size_t)tok * E_EXP + ex] = vh[r] + vc[r] * INV_SCALE;
            }
        }
}

// ---------------------------------------------------------------------------
// Routing: one wave per token. Sums nsplit planes. No atomics.
// ---------------------------------------------------------------------------
__global__ __launch_bounds__(256)
void routing_kernel(const float* __restrict__ planes,
                    const float* __restrict__ bias,
                    float* __restrict__ out_w,
                    float* __restrict__ out_i,
                    int nsplit) {
    const int wave = threadIdx.x >> 6;
    const int lane = threadIdx.x & 63;
    const int t    = blockIdx.x * 4 + wave;

    float lg[4] = {0.f, 0.f, 0.f, 0.f};
    for (int s = 0; s < nsplit; s++) {
        const float4 l = *(const float4*)(planes + (size_t)s * T_TOK * E_EXP +
                                          (size_t)t * E_EXP + lane * 4);
        lg[0] += l.x; lg[1] += l.y; lg[2] += l.z; lg[3] += l.w;
    }
    const float4 bi = *(const float4*)(bias + lane * 4);

    float orig[4], s[4];
    #pragma unroll
    for (int j = 0; j < 4; j++)
        orig[j] = 1.0f / (1.0f + expf(-lg[j]));
    s[0] = orig[0] + bi.x; s[1] = orig[1] + bi.y;
    s[2] = orig[2] + bi.z; s[3] = orig[3] + bi.w;

    float p1 = fmaxf(s[0], s[1]), p2 = fminf(s[0], s[1]);
    float q1 = fmaxf(s[2], s[3]), q2 = fminf(s[2], s[3]);
    float m1 = fmaxf(p1, q1);
    float m2 = fmaxf(fminf(p1, q1), (p1 >= q1) ? p2 : q2);

    #pragma unroll
    for (int off = 1; off <= 4; off <<= 1) {
        float o1 = __shfl_xor(m1, off);
        float o2 = __shfl_xor(m2, off);
        float M1 = fmaxf(m1, o1);
        float M2 = fmaxf(fminf(m1, o1), (m1 >= o1) ? m2 : o2);
        m1 = M1; m2 = M2;
    }
    const float gscore = m1 + m2;

    const int g = lane >> 3;
    int cnt = 0;
    #pragma unroll
    for (int j = 0; j < G_GRP; j++) {
        float gj = __shfl(gscore, j * 8);
        cnt += (gj > gscore || (gj == gscore && j < g)) ? 1 : 0;
    }
    const bool keep = (cnt < LG_GRP);

    float smask[4];
    #pragma unroll
    for (int j = 0; j < 4; j++) smask[j] = keep ? s[j] : -INFINITY;

    float wsum = 0.0f, my_o = 0.0f;
    int my_i = 0;

    #pragma unroll
    for (int k = 0; k < K_SEL; k++) {
        float bv = smask[0]; float bo = orig[0]; int bs = 0;
        if (smask[1] > bv) { bv = smask[1]; bo = orig[1]; bs = 1; }
        if (smask[2] > bv) { bv = smask[2]; bo = orig[2]; bs = 2; }
        if (smask[3] > bv) { bv = smask[3]; bo = orig[3]; bs = 3; }
        int bidx = lane * 4 + bs;

        #pragma unroll
        for (int off = 32; off >= 1; off >>= 1) {
            float ov = __shfl_xor(bv, off);
            float oo = __shfl_xor(bo, off);
            int   oi = __shfl_xor(bidx, off);
            if (ov > bv || (ov == bv && oi < bidx)) { bv = ov; bo = oo; bidx = oi; }
        }
        wsum += bo;
        if (lane == k) { my_o = bo; my_i = bidx; }
        if ((bidx >> 2) == lane) {
            const int sl = bidx & 3;
            smask[0] = (sl == 0) ? -INFINITY : smask[0];
            smask[1] = (sl == 1) ? -INFINITY : smask[1];
            smask[2] = (sl == 2) ? -INFINITY : smask[2];
            smask[3] = (sl == 3) ? -INFINITY : smask[3];
        }
    }

    if (lane < K_SEL) {
        out_w[(size_t)t * K_SEL + lane] = my_o * ROUTE_SCALE / wsum;
        out_i[(size_t)t * K_SEL + lane] = (float)my_i;
    }
}

// ---------------------------------------------------------------------------
// Counts: block e scans all T*K indices for expert e. L2-hot, zero atomics.
// ---------------------------------------------------------------------------
__global__ __launch_bounds__(256)
void count_kernel(const float* __restrict__ idxf, float* __restrict__ out_c) {
    const float fe = (float)blockIdx.x;
    int c = 0;
    const float4* p = (const float4*)idxf;          // T*K/4 = 16384
    for (int i = threadIdx.x; i < (T_TOK * K_SEL / 4); i += 256) {
        float4 v = p[i];
        c += (v.x == fe) + (v.y == fe) + (v.z == fe) + (v.w == fe);
    }
    __shared__ int red[4];
    #pragma unroll
    for (int off = 32; off >= 1; off >>= 1) c += __shfl_down(c, off);
    if ((threadIdx.x & 63) == 0) red[threadIdx.x >> 6] = c;
    __syncthreads();
    if (threadIdx.x == 0)
        out_c[blockIdx.x] = (float)(red[0] + red[1] + red[2] + red[3]);
}

// ---------------- launch ----------------
extern "C" void kernel_launch(void* const* d_in, const int* in_sizes, int n_in,
                              void* d_out, int out_size, void* d_ws, size_t ws_size,
                              hipStream_t stream) {
    const float* x    = (const float*)d_in[0];
    const float* W    = (const float*)d_in[1];
    const float* bias = (const float*)d_in[2];

    float* out   = (float*)d_out;
    float* out_w = out;
    float* out_i = out + (size_t)T_TOK * K_SEL;
    float* out_c = out + (size_t)2 * T_TOK * K_SEL;

    const size_t planeN  = (size_t)T_TOK * E_EXP;              // floats per plane
    const size_t wfBytes = (size_t)2 * WF_HALVES_PER_H * sizeof(half_t);

    // split-K=3 (grid 768 = 3 blocks/CU at 48 KB LDS); fallback split-K=2.
    int nsplit = 3;
    if (ws_size != 0 && ws_size < 3 * planeN * sizeof(float) + wfBytes)
        nsplit = 2;
    const int grid = 128 * 2 * nsplit;

    float* planes = (float*)d_ws;
    half_t* Wf    = (half_t*)(planes + (size_t)nsplit * planeN);

    hipLaunchKernelGGL(convert_W_kernel, dim3(896), dim3(256), 0, stream, W, Wf);
    hipLaunchKernelGGL(gemm_logits_f16split, dim3(grid), dim3(256), 0, stream,
                       x, Wf, planes, nsplit);
    hipLaunchKernelGGL(routing_kernel, dim3(T_TOK / 4), dim3(256), 0, stream,
                       planes, bias, out_w, out_i, nsplit);
    hipLaunchKernelGGL(count_kernel, dim3(E_EXP), dim3(256), 0, stream,
                       out_i, out_c);
}